// Round 13
// baseline (83.651 us; speedup 1.0000x reference)
//
#include <hip/hip_runtime.h>

// Fully-fused 4-layer MLP via f16 MFMA (fp32 accumulate), transposed problem
// G = H^T: activations live in registers across all layers (B operand).
// R13: (a) bias folded into the matmul as an extra K-row (K 256->272, L1 uses
// the existing 13->16 pad; activation k=K slot = 1.0) -> repack is pure
// relu+pack+swap, no bias LDS reads/adds. (b) One phase per HALF-LAYER:
// 68 KB regions (4 nt x 17 ks), 6 barriers total, huge straight-line regions.
// One 1024-thread block (16 waves) per CU, grid 256, single generation.

typedef _Float16 half_t;
typedef _Float16 half8 __attribute__((ext_vector_type(8)));
typedef float f32x16 __attribute__((ext_vector_type(16)));
typedef unsigned int uint4v __attribute__((ext_vector_type(4)));
typedef int int2v __attribute__((ext_vector_type(2)));

#define M_TOTAL (64*2048)
#define NBLK 331           // 8 (L1) + 136 (L2) + 136 (L3) + 51 (L4) fragment blocks

// wp offsets in halves (block = 512 halves = 1 KB)
#define L2_OFF (8*512)
#define L3_OFF (144*512)
#define L4_OFF (280*512)
#define HSTRIP (17*4*512)  // 34816 halves = 68 KB (4 nt x 17 ks)

// ---------------- prep kernel ----------------
// Per-layer, nt-major, 17 ks-blocks per nt (L1: 1 ks-block). Within a block:
// wp[blk*512 + lane*8 + j] = Wrow(k)[nt*32 + (lane&31)], k = ks*16+(lane>>5)*8+j
// where Wrow(k) = W[k] for k<K, bias for k==K, 0 beyond.
__global__ void prep_w(const float* __restrict__ W1, const float* __restrict__ b1,
                       const float* __restrict__ W2, const float* __restrict__ b2,
                       const float* __restrict__ W3, const float* __restrict__ b3,
                       const float* __restrict__ W4, const float* __restrict__ b4,
                       half_t* __restrict__ wp) {
    int tid = blockIdx.x * 256 + threadIdx.x;
    if (tid >= NBLK * 512) return;
    int blk = tid >> 9, r = tid & 511, lane = r >> 3, j = r & 7;
    const float* W; const float* bias; int K, N, nt, ks;
    if (blk < 8)        { W = W1; bias = b1; K = 13;  N = 256; nt = blk; ks = 0; }
    else if (blk < 144) { int b = blk - 8;   W = W2; bias = b2; K = 256; N = 256; nt = b / 17; ks = b % 17; }
    else if (blk < 280) { int b = blk - 144; W = W3; bias = b3; K = 256; N = 256; nt = b / 17; ks = b % 17; }
    else                { int b = blk - 280; W = W4; bias = b4; K = 256; N = 80;  nt = b / 17; ks = b % 17; }
    int k = ks * 16 + (lane >> 5) * 8 + j;
    int n = nt * 32 + (lane & 31);
    float v = 0.f;
    if (n < N) {
        if (k < K)       v = W[k * N + n];
        else if (k == K) v = bias[n];      // bias row (k=13 for L1, k=256 for L2-4)
    }
    wp[tid] = (half_t)v;
}

// ---------------- main kernel ----------------

__device__ __forceinline__ unsigned int pkrtz(float a, float b) {
    auto p = __builtin_amdgcn_cvt_pkrtz(a, b);
    return __builtin_bit_cast(unsigned int, p);
}

typedef const __attribute__((address_space(1))) unsigned int guint_t;
typedef __attribute__((address_space(3))) unsigned int luint_t;

// Stage `bytes` from g into LDS l. 1024 threads x 16 B rounds + remainder.
__device__ __forceinline__ void stage(const half_t* __restrict__ g,
                                      half_t* l, int bytes, int tid) {
    const char* gc = (const char*)g;
    char* lc = (char*)l;
    const int go = tid * 16;
    const int lo = (tid >> 6) << 10;     // wave-uniform LDS offset (wave*1024)
    int r = 0;
#pragma unroll
    for (; r + 16384 <= bytes; r += 16384)
        __builtin_amdgcn_global_load_lds((guint_t*)(gc + r + go),
                                         (luint_t*)(lc + r + lo), 16, 0, 0);
    if ((bytes & 16383) && go < (bytes & 16383))
        __builtin_amdgcn_global_load_lds((guint_t*)(gc + r + go),
                                         (luint_t*)(lc + r + lo), 16, 0, 0);
}

#define PIPE_BAR0 do {                                        \
    asm volatile("s_waitcnt vmcnt(0)" ::: "memory");          \
    __builtin_amdgcn_sched_barrier(0);                        \
    __builtin_amdgcn_s_barrier();                             \
    __builtin_amdgcn_sched_barrier(0);                        \
} while (0)

#define MFMA16(a, b, c) __builtin_amdgcn_mfma_f32_32x32x16_f16((a), (b), (c), 0, 0, 0)

__device__ __forceinline__ half8 bw_cast(const unsigned int* w) {
    uint4v t = { w[0], w[1], w[2], w[3] };
    return __builtin_bit_cast(half8, t);
}

// Repack one C fragment (no bias!) into 2 B-slots (4 words each).
template <bool RELU>
__device__ __forceinline__ void repack2(const f32x16& acc, bool hi,
                                        unsigned int* B0, unsigned int* B1)
{
#pragma unroll
    for (int s = 0; s < 2; ++s) {
        unsigned int* Bw = s ? B1 : B0;
        float v[8];
#pragma unroll
        for (int q = 0; q < 8; ++q) {
            float t = acc[8 * s + q];
            v[q] = RELU ? fmaxf(t, 0.f) : t;
        }
        unsigned int P0 = pkrtz(v[0], v[1]);
        unsigned int P1 = pkrtz(v[2], v[3]);
        unsigned int P2 = pkrtz(v[4], v[5]);
        unsigned int P3 = pkrtz(v[6], v[7]);
        int2v r02 = __builtin_amdgcn_permlane32_swap((int)P0, (int)P2, false, false);
        int2v r13 = __builtin_amdgcn_permlane32_swap((int)P1, (int)P3, false, false);
        Bw[0] = (unsigned int)r02.x;
        Bw[1] = (unsigned int)r13.x;
        Bw[2] = (unsigned int)r02.y;
        Bw[3] = (unsigned int)r13.y;
    }
}

// Half-layer: 4 nt tiles x 17 ks (16 data + 1 bias row with const-1 B slot).
template <bool RELU>
__device__ __forceinline__ void dense4(const half_t* rg,
                                       const unsigned int (&Bin)[16][4],
                                       unsigned int (&Bout)[16][4],
                                       int ntbase, int lane, bool hi,
                                       unsigned int cw)
{
#pragma unroll
    for (int t = 0; t < 4; ++t) {
        const half_t* astrip = rg + t * 17 * 512;
        f32x16 acc = {};
        __builtin_amdgcn_s_setprio(1);
#pragma unroll
        for (int ks = 0; ks < 16; ++ks) {
            half8 a = *(const half8*)(astrip + ((ks * 64 + lane) << 3));
            acc = MFMA16(a, bw_cast(Bin[ks]), acc);
        }
        {   // bias row: B slot = 1.0 at k=K (lo-half word0 low), else 0
            half8 a = *(const half8*)(astrip + ((16 * 64 + lane) << 3));
            uint4v cb = { cw, 0u, 0u, 0u };
            acc = MFMA16(a, __builtin_bit_cast(half8, cb), acc);
        }
        __builtin_amdgcn_s_setprio(0);
        repack2<RELU>(acc, hi, Bout[2 * (ntbase + t)], Bout[2 * (ntbase + t) + 1]);
    }
}

__global__ __launch_bounds__(1024, 1) void mlp_mfma(
    const float* __restrict__ x, const half_t* __restrict__ wp,
    float* __restrict__ out)
{
    // Regions (halves): R0 = L1 (8 KB) @0; R1 (68 KB) @4096; R2 (68 KB) @38912.
    __shared__ half_t lds[73728];        // 144 KB

    const int tid  = threadIdx.x;
    const int lane = tid & 63;
    const int wave = tid >> 6;
    const bool hi  = lane >= 32;
    const int m0   = blockIdx.x * 512 + wave * 32;   // 32 samples per wave
    const unsigned int cw = hi ? 0u : 0x3C00u;       // f16 1.0 in k=K slot

    stage(wp,          lds,         8192,  tid);     // L1 -> R0
    stage(wp + L2_OFF, lds + 4096,  69632, tid);     // L2a -> R1

    // Layer-1 B fragment from fp32 x; k=13 slot = 1.0 (bias row), 14,15 = 0
    unsigned int Bx[4];
    {
        const float* xp = x + (long)(m0 + (lane & 31)) * 13;
        float xv[8];
        if (!hi) {
#pragma unroll
            for (int j = 0; j < 8; ++j) xv[j] = xp[j];
        } else {
#pragma unroll
            for (int j = 0; j < 5; ++j) xv[j] = xp[8 + j];
            xv[5] = 1.0f;               // k = 13: bias row multiplier
            xv[6] = xv[7] = 0.f;
        }
        Bx[0] = pkrtz(xv[0], xv[1]);
        Bx[1] = pkrtz(xv[2], xv[3]);
        Bx[2] = pkrtz(xv[4], xv[5]);
        Bx[3] = pkrtz(xv[6], xv[7]);
    }

    PIPE_BAR0;   // entry: L1 + L2a resident, x loaded

    unsigned int BA[16][4], BB[16][4];

    // ---- P0+P1 (no barrier between): L1 then L2a ----
    stage(wp + L2_OFF + HSTRIP, lds + 38912, 69632, tid);   // L2b -> R2
    {
        half8 bx = bw_cast(Bx);
#pragma unroll
        for (int nt = 0; nt < 8; ++nt) {
            half8 a = *(const half8*)(lds + nt * 512 + (lane << 3));
            f32x16 acc = {};
            acc = MFMA16(a, bx, acc);
            repack2<true>(acc, hi, BB[2 * nt], BB[2 * nt + 1]);
        }
    }
    dense4<true>(lds + 4096, BB, BA, 0, lane, hi, cw);      // L2 nt0-3
    PIPE_BAR0;   // L2b drained; R1 free

    stage(wp + L3_OFF, lds + 4096, 69632, tid);             // L3a -> R1
    dense4<true>(lds + 38912, BB, BA, 4, lane, hi, cw);     // L2 nt4-7 (R2)
    PIPE_BAR0;   // L3a drained; R2 free

    stage(wp + L3_OFF + HSTRIP, lds + 38912, 69632, tid);   // L3b -> R2
    dense4<true>(lds + 4096, BA, BB, 0, lane, hi, cw);      // L3 nt0-3 (R1)
    PIPE_BAR0;   // L3b drained; R1 free

    stage(wp + L4_OFF, lds + 4096, 52224, tid);             // L4 -> R1 (51 KB)
    dense4<true>(lds + 38912, BA, BB, 4, lane, hi, cw);     // L3 nt4-7 (R2)
    PIPE_BAR0;   // L4 drained

    // ---- P5: L4 (3 nt x 17 ks), no ReLU, direct stores ----
#pragma unroll
    for (int t = 0; t < 3; ++t) {
        const half_t* astrip = lds + 4096 + t * 17 * 512;
        f32x16 acc = {};
        __builtin_amdgcn_s_setprio(1);
#pragma unroll
        for (int ks = 0; ks < 16; ++ks) {
            half8 a = *(const half8*)(astrip + ((ks * 64 + lane) << 3));
            acc = MFMA16(a, bw_cast(BB[ks]), acc);
        }
        {
            half8 a = *(const half8*)(astrip + ((16 * 64 + lane) << 3));
            uint4v cb = { cw, 0u, 0u, 0u };
            acc = MFMA16(a, __builtin_bit_cast(half8, cb), acc);
        }
        __builtin_amdgcn_s_setprio(0);
        float* orow = out + (long)(m0 + (lane & 31)) * 80 + t * 32;
#pragma unroll
        for (int reg = 0; reg < 16; ++reg) {
            if (t == 2 && (reg >> 2) >= 2) continue;   // f = 64+rr < 80 <=> rr < 16
            int rr = (reg & 3) + 8 * (reg >> 2) + (hi ? 4 : 0);
            orow[rr] = acc[reg];
        }
    }
}

// ---------------- launch ----------------

extern "C" void kernel_launch(void* const* d_in, const int* in_sizes, int n_in,
                              void* d_out, int out_size, void* d_ws, size_t ws_size,
                              hipStream_t stream) {
    const float* x  = (const float*)d_in[0];
    const float* W1 = (const float*)d_in[1];
    const float* b1 = (const float*)d_in[2];
    const float* W2 = (const float*)d_in[3];
    const float* b2 = (const float*)d_in[4];
    const float* W3 = (const float*)d_in[5];
    const float* b3 = (const float*)d_in[6];
    const float* W4 = (const float*)d_in[7];
    const float* b4 = (const float*)d_in[8];
    float* out = (float*)d_out;

    half_t* wp = (half_t*)d_ws;          // 331 KB of prepped weights

    hipLaunchKernelGGL(prep_w, dim3((NBLK * 512 + 255) / 256), dim3(256), 0, stream,
                       W1, b1, W2, b2, W3, b3, W4, b4, wp);
    hipLaunchKernelGGL(mlp_mfma, dim3(M_TOTAL / 512), dim3(1024), 0, stream,
                       x, wp, out);
}